// Round 6
// baseline (96.245 us; speedup 1.0000x reference)
//
#include <hip/hip_runtime.h>

// IntegerNeuron: spiking-neuron scan over T with soft reset.
// x_accum [T,B,C,H,W] f32; per-channel scale/bias/vth [C]; tau scalar; is_first_layer int.
// out = spikes [T,B,C,H,W] f32 (0.0 or 1.0).
//
// Pure streaming op (zero reuse): 256 MiB read + 256 MiB write. Floor at the
// 6.3 TB/s mixed-stream ceiling = 85us.
// R1: float4 + reg-carried mem -> 118us (4.5 TB/s).
// R2: non-temporal loads/stores -> 100us (5.4 TB/s).
// R3: 1024-thread blocks -> 118us REGRESSED. Reverted.
// R4: 2 float4/thread -> 95us (5.65 TB/s). Latency-bound; ILP is the lever.
// R5: 4 float4/thread (wave owns a plane) -> 89.5us (6.0 TB/s).
// R6: 8 float4/thread (wave owns 2 planes, grid 1024): last ILP doubling.
//     Positions p=0..3 -> plane A (channel cA), p=4..7 -> plane B (cB).
//
// Bit-exactness vs numpy f32 reference is mandatory (binary output):
//  - rintf (half-to-even) to match np.round
//  - explicit __fmul_rn/__fadd_rn so no FMA contraction changes mem rounding
//  - op order matches reference exactly: ((mem + x*tau) + bias_scaled)

#define T_STEPS 8
#define C_CH    256
#define HW      1024
#define EPS_F   1e-12f
#define NPOS    8    // float4 positions per thread (4 in each of 2 planes)

typedef float v4f __attribute__((ext_vector_type(4)));

__global__ __launch_bounds__(256) void integer_neuron_kernel(
    const float* __restrict__ x,          // [T, B*C*HW]
    const float* __restrict__ prev_scale, // [C]
    const float* __restrict__ prev_bias,  // [C]
    const float* __restrict__ vth,        // [C]
    const float* __restrict__ tau_p,      // [1]
    const int*   __restrict__ is_first_p, // [1]
    float* __restrict__ out,              // [T, B*C*HW]
    long long n_planes)                   // B*C
{
    const float tau      = tau_p[0];
    const int   is_first = is_first_p[0];
    // drive = x_accum if is_first else x_accum * tau. Multiplying by exactly
    // 1.0f is bit-identical to the identity for finite inputs.
    const float drive_mul = is_first ? 1.0f : tau;

    // Each wave owns 2 consecutive planes (2048 floats): lane l covers float4
    // positions l + 64*p for p=0..7; p<4 lie in plane A, p>=4 in plane B.
    // Block = 4 waves = 8 planes.
    const long long planeA = (long long)blockIdx.x * 8 + (threadIdx.x >> 6) * 2;
    const int cA = (int)(planeA % C_CH);
    const int cB = (int)((planeA + 1) % C_CH);

    // Per-channel constants; exact reference op order:
    //   round(b*tau/(s+EPS)), round(v*tau/(s+EPS)) with round = half-to-even.
    const float denomA = __fadd_rn(prev_scale[cA], EPS_F);
    const float biasA  = rintf(__fdiv_rn(__fmul_rn(prev_bias[cA], tau), denomA));
    const float vthA   = rintf(__fdiv_rn(__fmul_rn(vth[cA],       tau), denomA));
    const float denomB = __fadd_rn(prev_scale[cB], EPS_F);
    const float biasB  = rintf(__fdiv_rn(__fmul_rn(prev_bias[cB], tau), denomB));
    const float vthB   = rintf(__fdiv_rn(__fmul_rn(vth[cB],       tau), denomB));

    const long long N    = n_planes * (long long)HW;     // stride per time step
    const long long base = planeA * (long long)HW
                         + (long long)(threadIdx.x & 63) * 4;

    float mem[NPOS][4];
    #pragma unroll
    for (int p = 0; p < NPOS; ++p)
        #pragma unroll
        for (int j = 0; j < 4; ++j)
            mem[p][j] = 0.0f;

    #pragma unroll
    for (int t = 0; t < T_STEPS; ++t) {
        const long long off = (long long)t * N + base;

        v4f xv[NPOS];
        #pragma unroll
        for (int p = 0; p < NPOS; ++p)
            xv[p] = __builtin_nontemporal_load(
                reinterpret_cast<const v4f*>(x + off + p * 256));

        v4f sp[NPOS];
        #pragma unroll
        for (int p = 0; p < NPOS; ++p) {
            const float bias_scaled = (p < 4) ? biasA : biasB;
            const float vth_scaled  = (p < 4) ? vthA  : vthB;
            #pragma unroll
            for (int j = 0; j < 4; ++j) {
                float m = mem[p][j];
                m = __fadd_rn(__fadd_rn(m, __fmul_rn(xv[p][j], drive_mul)), bias_scaled);
                const float s = (m >= vth_scaled) ? 1.0f : 0.0f;
                mem[p][j] = __fsub_rn(m, __fmul_rn(s, vth_scaled));
                sp[p][j] = s;
            }
        }

        #pragma unroll
        for (int p = 0; p < NPOS; ++p)
            __builtin_nontemporal_store(sp[p],
                reinterpret_cast<v4f*>(out + off + p * 256));
    }
}

extern "C" void kernel_launch(void* const* d_in, const int* in_sizes, int n_in,
                              void* d_out, int out_size, void* d_ws, size_t ws_size,
                              hipStream_t stream) {
    const float* x          = (const float*)d_in[0]; // [T,B,C,H,W]
    const float* prev_scale = (const float*)d_in[1]; // [C]
    const float* prev_bias  = (const float*)d_in[2]; // [C]
    const float* vth        = (const float*)d_in[3]; // [C]
    const float* tau        = (const float*)d_in[4]; // [1]
    const int*   is_first   = (const int*)d_in[5];   // [1]
    float* out = (float*)d_out;

    // total elems = T * n_planes * HW; n_planes = B*C
    const long long total    = (long long)out_size;
    const long long n_planes = total / ((long long)T_STEPS * HW);

    dim3 grid((unsigned)(n_planes / 8));  // 1024 blocks, 8 planes each
    dim3 block(256);
    integer_neuron_kernel<<<grid, block, 0, stream>>>(
        x, prev_scale, prev_bias, vth, tau, is_first, out, n_planes);
}

// Round 7
// 89.761 us; speedup vs baseline: 1.0722x; 1.0722x over previous
//
#include <hip/hip_runtime.h>

// IntegerNeuron: spiking-neuron scan over T with soft reset.
// x_accum [T,B,C,H,W] f32; per-channel scale/bias/vth [C]; tau scalar; is_first_layer int.
// out = spikes [T,B,C,H,W] f32 (0.0 or 1.0).
//
// Pure streaming op (zero reuse): 256 MiB read + 256 MiB write. Floor at the
// 6.3 TB/s mixed-stream ceiling = 85us.
// R1: float4 + reg-carried mem -> 118us (4.5 TB/s).
// R2: non-temporal loads/stores -> 100us (5.4 TB/s).
// R3: 1024-thread blocks -> 118us REGRESSED. Reverted.
// R4: 2 float4/thread -> 95us (5.65 TB/s). Latency-bound; ILP is the lever.
// R5: 4 float4/thread (wave owns a plane) -> 89.5us (6.0 TB/s).  <-- OPTIMUM
// R6: 8 float4/thread -> 96us REGRESSED (VGPR/store-queue pressure).
// R7: revert to R5. 6.0 TB/s = 95% of the 6.3 TB/s achievable mixed-stream
//     ceiling; byte count is compulsory (read once, write once) -> roofline.
//
// Bit-exactness vs numpy f32 reference is mandatory (binary output):
//  - rintf (half-to-even) to match np.round
//  - explicit __fmul_rn/__fadd_rn so no FMA contraction changes mem rounding
//  - op order matches reference exactly: ((mem + x*tau) + bias_scaled)

#define T_STEPS 8
#define C_CH    256
#define HW      1024
#define EPS_F   1e-12f
#define NPOS    4    // float4 positions per thread

typedef float v4f __attribute__((ext_vector_type(4)));

__global__ __launch_bounds__(256) void integer_neuron_kernel(
    const float* __restrict__ x,          // [T, B*C*HW]
    const float* __restrict__ prev_scale, // [C]
    const float* __restrict__ prev_bias,  // [C]
    const float* __restrict__ vth,        // [C]
    const float* __restrict__ tau_p,      // [1]
    const int*   __restrict__ is_first_p, // [1]
    float* __restrict__ out,              // [T, B*C*HW]
    long long n_planes)                   // B*C
{
    const float tau      = tau_p[0];
    const int   is_first = is_first_p[0];
    // drive = x_accum if is_first else x_accum * tau. Multiplying by exactly
    // 1.0f is bit-identical to the identity for finite inputs.
    const float drive_mul = is_first ? 1.0f : tau;

    // Each wave (64 lanes) owns one full HW plane: lane l covers float4
    // positions l, l+64, l+128, l+192. Block = 4 waves = 4 planes.
    const long long plane = (long long)blockIdx.x * 4 + (threadIdx.x >> 6);
    const int c = (int)(plane % C_CH);

    // Per-channel constants; exact reference op order:
    //   round(b*tau/(s+EPS)), round(v*tau/(s+EPS)) with round = half-to-even.
    const float denom       = __fadd_rn(prev_scale[c], EPS_F);
    const float bias_scaled = rintf(__fdiv_rn(__fmul_rn(prev_bias[c], tau), denom));
    const float vth_scaled  = rintf(__fdiv_rn(__fmul_rn(vth[c],       tau), denom));

    const long long N    = n_planes * (long long)HW;     // stride per time step
    const long long base = plane * (long long)HW
                         + (long long)(threadIdx.x & 63) * 4;

    float mem[NPOS][4];
    #pragma unroll
    for (int p = 0; p < NPOS; ++p)
        #pragma unroll
        for (int j = 0; j < 4; ++j)
            mem[p][j] = 0.0f;

    #pragma unroll
    for (int t = 0; t < T_STEPS; ++t) {
        const long long off = (long long)t * N + base;

        v4f xv[NPOS];
        #pragma unroll
        for (int p = 0; p < NPOS; ++p)
            xv[p] = __builtin_nontemporal_load(
                reinterpret_cast<const v4f*>(x + off + p * 256));

        v4f sp[NPOS];
        #pragma unroll
        for (int p = 0; p < NPOS; ++p) {
            #pragma unroll
            for (int j = 0; j < 4; ++j) {
                float m = mem[p][j];
                m = __fadd_rn(__fadd_rn(m, __fmul_rn(xv[p][j], drive_mul)), bias_scaled);
                const float s = (m >= vth_scaled) ? 1.0f : 0.0f;
                mem[p][j] = __fsub_rn(m, __fmul_rn(s, vth_scaled));
                sp[p][j] = s;
            }
        }

        #pragma unroll
        for (int p = 0; p < NPOS; ++p)
            __builtin_nontemporal_store(sp[p],
                reinterpret_cast<v4f*>(out + off + p * 256));
    }
}

extern "C" void kernel_launch(void* const* d_in, const int* in_sizes, int n_in,
                              void* d_out, int out_size, void* d_ws, size_t ws_size,
                              hipStream_t stream) {
    const float* x          = (const float*)d_in[0]; // [T,B,C,H,W]
    const float* prev_scale = (const float*)d_in[1]; // [C]
    const float* prev_bias  = (const float*)d_in[2]; // [C]
    const float* vth        = (const float*)d_in[3]; // [C]
    const float* tau        = (const float*)d_in[4]; // [1]
    const int*   is_first   = (const int*)d_in[5];   // [1]
    float* out = (float*)d_out;

    // total elems = T * n_planes * HW; n_planes = B*C
    const long long total    = (long long)out_size;
    const long long n_planes = total / ((long long)T_STEPS * HW);

    dim3 grid((unsigned)(n_planes / 4));  // 2048 blocks, 4 planes each
    dim3 block(256);
    integer_neuron_kernel<<<grid, block, 0, stream>>>(
        x, prev_scale, prev_bias, vth, tau, is_first, out, n_planes);
}